// Round 2
// baseline (18134.595 us; speedup 1.0000x reference)
//
#include <hip/hip_runtime.h>
#include <math.h>

// ---------------------------------------------------------------------------
// SimpleRNN (2-layer LSTM, H=1024, T=4096 sequential steps, batch=1 effective)
//
//   k_clear    : zero the packet buffers (tags must start invalid)
//   k_prep     : gather x (step-major), combine biases
//   gemm_nt    : C[M,N] = A[M,K] @ B[N,K]^T + bias
//   lstm_fused : ONE persistent 256-block kernel, both layer chains, layer-1
//                pipelined one step behind layer-0 (4097 round slots).
//                SYNC = DATA: h travels as 8-byte packets {float h, int tag}
//                via relaxed agent-scope 64-bit stores.
//                R7 post-mortem: poll-contention theory wrong (FETCH -14% but
//                round 2.44->2.30us only). Round is a LATENCY CHAIN.
//   R8: chain-shortening rewrite of lstm_fused:
//       - 512 threads/block (8 waves). ONE __syncthreads per round (16-wave
//         barriers x2 -> 8-wave x1), h double-buffered in LDS.
//       - wave w owns hidden unit j0+w: its 4 gate rows live in the wave.
//         After butterfly all-reduce, lanes 0..3 hold the 4 gate sums ->
//         activations computed IN PARALLEL in-wave, combined via 3 shuffles,
//         packet stored by lane0. Deletes bar2 + scr LDS round-trip + serial
//         5-transcendental tail of the old layout.
//       - contiguous LDS layout: dot phase reads 4x ds_read_b128 (was 16
//         strided ds_read_b32); weights pre-gathered to match (float4 loads).
//       - poll: 2 packets per thread (512 threads cover 1024), fewer
//         transactions; pacing wake earlier (0.375*per) to remove any
//         EWMA fixed-point risk.
// ---------------------------------------------------------------------------

#define T_STEPS 4096
#define HID 1024
#define UPB 8            // hidden units per block (= waves per block)
#define NBLK 256         // persistent blocks (128 per layer)

typedef unsigned long long u64;

#define AGENT_LD64(p) __hip_atomic_load((p), __ATOMIC_RELAXED, __HIP_MEMORY_SCOPE_AGENT)
#define AGENT_ST64(p, v) __hip_atomic_store((p), (v), __ATOMIC_RELAXED, __HIP_MEMORY_SCOPE_AGENT)

__device__ __forceinline__ u64 pack_h(float h, int tag) {
  return (u64)__float_as_uint(h) | ((u64)(unsigned)tag << 32);
}
__device__ __forceinline__ float pkt_val(u64 v) { return __uint_as_float((unsigned)v); }
__device__ __forceinline__ int pkt_tag(u64 v) { return (int)(v >> 32); }

__device__ __forceinline__ float fast_sigm(float x) {
  return __builtin_amdgcn_rcpf(1.f + __expf(-x));
}
__device__ __forceinline__ float fast_tanh(float x) {
  return 2.f * __builtin_amdgcn_rcpf(1.f + __expf(-2.f * x)) - 1.f;
}

// Pace: sleep (no memory traffic) until ~0.375 of the expected period has
// elapsed since the previous detect. per==0 disables (warmup rounds).
__device__ __forceinline__ void pace_wait(u64 t_last, u64 per) {
  if (per) {
    u64 target = t_last + (per >> 2) + (per >> 3);   // t_last + 0.375*per
    while ((long long)(__builtin_amdgcn_s_memrealtime() - target) < 0)
      __builtin_amdgcn_s_sleep(2);
  }
}
// EWMA period update (clamped against scheduler hiccups).
__device__ __forceinline__ void pace_update(u64* t_last, u64* per) {
  u64 now = __builtin_amdgcn_s_memrealtime();
  if (*t_last) {
    u64 d = now - *t_last;
    if (d > 1024) d = 1024;                 // ~10 us cap @100 MHz wall clock
    *per = *per ? ((*per * 3 + d) >> 2) : d;
  }
  *t_last = now;
}

__global__ void k_clear(u64* __restrict__ p, long n) {
  long i = (long)blockIdx.x * blockDim.x + threadIdx.x;
  long stride = (long)gridDim.x * blockDim.x;
  for (; i < n; i += stride) p[i] = 0ULL;
}

__global__ void k_prep(const float* __restrict__ inputs,
                       const float* __restrict__ b_ih0, const float* __restrict__ b_hh0,
                       const float* __restrict__ b_ih1, const float* __restrict__ b_hh1,
                       float* __restrict__ xg, float* __restrict__ bsum0,
                       float* __restrict__ b1sum) {
  int i = blockIdx.x * 256 + threadIdx.x;   // grid covers 262144
  if (i < T_STEPS * 64) {
    int t = i >> 6, d = i & 63;
    // x[t] = inputs[sample = t%32, step = t/32, :]
    xg[i] = inputs[(t & 31) * 8192 + (t >> 5) * 64 + d];
  }
  if (i < 4096) {
    bsum0[i] = b_ih0[i] + b_hh0[i];
    b1sum[i] = b_ih1[i] + b_hh1[i];
  }
}

// C = A @ B^T + bias.  A: M x K, B: N x K (both row-major, K contiguous).
// 128x128 tile, BK=8, 256 threads, 8x8 micro-tile per thread.
__global__ __launch_bounds__(256) void gemm_nt(
    const float* __restrict__ A, const float* __restrict__ B,
    const float* __restrict__ bias, float* __restrict__ C,
    int M, int N, int K, int mode) {
  __shared__ float As[8][128];
  __shared__ float Bs[8][128];
  const int tid = threadIdx.x;
  const int bm = blockIdx.x * 128;
  const int bn = blockIdx.y * 128;
  const int tm = tid >> 4;
  const int tn = tid & 15;
  const int lr = tid >> 1;
  const int lk = (tid & 1) * 4;

  float acc[8][8];
#pragma unroll
  for (int i = 0; i < 8; i++)
#pragma unroll
    for (int j = 0; j < 8; j++) acc[i][j] = 0.f;

  const float* Ap = A + (long)(bm + lr) * K + lk;
  const bool bvalid = (bn + lr) < N;
  const float* Bp = B + (long)(bvalid ? (bn + lr) : 0) * K + lk;

  for (int k0 = 0; k0 < K; k0 += 8) {
    float4 av = *(const float4*)(Ap + k0);
    float4 bv = bvalid ? *(const float4*)(Bp + k0) : make_float4(0.f, 0.f, 0.f, 0.f);
    As[lk + 0][lr] = av.x; As[lk + 1][lr] = av.y;
    As[lk + 2][lr] = av.z; As[lk + 3][lr] = av.w;
    Bs[lk + 0][lr] = bv.x; Bs[lk + 1][lr] = bv.y;
    Bs[lk + 2][lr] = bv.z; Bs[lk + 3][lr] = bv.w;
    __syncthreads();
#pragma unroll
    for (int kk = 0; kk < 8; kk++) {
      float a[8], b[8];
      *(float4*)&a[0] = *(const float4*)&As[kk][tm * 8];
      *(float4*)&a[4] = *(const float4*)&As[kk][tm * 8 + 4];
      *(float4*)&b[0] = *(const float4*)&Bs[kk][tn * 8];
      *(float4*)&b[4] = *(const float4*)&Bs[kk][tn * 8 + 4];
#pragma unroll
      for (int i = 0; i < 8; i++)
#pragma unroll
        for (int j = 0; j < 8; j++) acc[i][j] = fmaf(a[i], b[j], acc[i][j]);
    }
    __syncthreads();
  }

  const int n0 = bn + tn * 8;
  if (n0 < N) {
    float bb[8];
#pragma unroll
    for (int j = 0; j < 8; j++) bb[j] = bias[n0 + j];
#pragma unroll
    for (int i = 0; i < 8; i++) {
      int m = bm + tm * 8 + i;
      float4 v0, v1;
      v0.x = acc[i][0] + bb[0]; v0.y = acc[i][1] + bb[1];
      v0.z = acc[i][2] + bb[2]; v0.w = acc[i][3] + bb[3];
      v1.x = acc[i][4] + bb[4]; v1.y = acc[i][5] + bb[5];
      v1.z = acc[i][6] + bb[6]; v1.w = acc[i][7] + bb[7];
      if (mode == 0) {
        long o = (long)m * N + n0;
        *(float4*)&C[o] = v0; *(float4*)&C[o + 4] = v1;
      } else {
        long o = (long)(m & 31) * 8192 + (long)(m >> 5) * 64 + n0;
        *(float4*)&C[o] = v0; *(float4*)&C[o + 4] = v1;
      }
    }
  }
}

// Fused 2-layer recurrence. 256 blocks x 512 threads (8 waves).
// Wave w owns hidden unit u = j0 + w: all 4 gate rows (i,f,g,o) of u.
// Contiguous LDS layout: lane l covers h-words {256q + 4l .. +3, q=0..3}
// (4x ds_read_b128, conflict-free); weights pre-gathered to match.
// One __syncthreads per round; h double-buffered by round parity.
__global__ __launch_bounds__(512) void lstm_fused(
    const float* __restrict__ pre0,   // T x 4096 (layer-0 biases included)
    const float* __restrict__ Whh0,   // 4096 x 1024
    const float* __restrict__ Wih1,   // 4096 x 1024
    const float* __restrict__ Whh1,   // 4096 x 1024
    const float* __restrict__ b1sum,  // 4096
    u64* __restrict__ pk0,            // T x 1024 packets {h0, tag=t+1}
    u64* __restrict__ pk1,            // T x 1024 packets {h1, tag=t+1}
    float* __restrict__ h1_hist) {    // T x 1024 plain (for output GEMM)
  __shared__ float ha[2][HID];        // 8 KB (double-buffered h input)
  __shared__ float hb[2][HID];        // 8 KB (layer-1 only: prev h1)
  const int b = blockIdx.x;
  const int tid = threadIdx.x;
  const int wave = tid >> 6;
  const int lane = tid & 63;

  if (b < 128) {
    // ----------------------------- layer 0 -------------------------------
    const int u = b * UPB + wave;     // this wave's hidden unit
    // wgt[g][q] = Whh0[g*1024+u][256q + 4*lane .. +3]
    float4 wgt[4][4];
#pragma unroll
    for (int g = 0; g < 4; g++)
#pragma unroll
      for (int q = 0; q < 4; q++)
        wgt[g][q] = *(const float4*)(Whh0 + ((long)((g << 10) + u) << 10) +
                                     (q << 8) + (lane << 2));
    float c_state = 0.f;              // valid in lane 0
    u64 t_last = 0, per = 0;          // pacing state (100 MHz wall ticks)

    for (int t = 0; t < T_STEPS; t++) {
      float preval = 0.f;             // issue early: overlaps sleep/poll
      if (lane < 4) preval = pre0[(long)t * 4096 + (lane << 10) + u];
      const int par = t & 1;

      if (t > 0) {
        const u64* p = pk0 + (long)(t - 1) * HID + 2 * tid;
        pace_wait(t_last, per);
        u64 v0, v1;
        for (;;) {
          v0 = AGENT_LD64(p); v1 = AGENT_LD64(p + 1);
          if (pkt_tag(v0) == t && pkt_tag(v1) == t) break;
          __builtin_amdgcn_s_sleep(1);
        }
        pace_update(&t_last, &per);
        *(float2*)&ha[par][2 * tid] = make_float2(pkt_val(v0), pkt_val(v1));
      } else {
        *(float2*)&ha[par][2 * tid] = make_float2(0.f, 0.f);
      }
      __syncthreads();                // the ONLY barrier this round

      float s0 = 0.f, s1 = 0.f, s2 = 0.f, s3 = 0.f;
#pragma unroll
      for (int q = 0; q < 4; q++) {
        float4 hv = *(const float4*)&ha[par][(q << 8) + (lane << 2)];
        s0 = fmaf(wgt[0][q].x, hv.x, s0); s0 = fmaf(wgt[0][q].y, hv.y, s0);
        s0 = fmaf(wgt[0][q].z, hv.z, s0); s0 = fmaf(wgt[0][q].w, hv.w, s0);
        s1 = fmaf(wgt[1][q].x, hv.x, s1); s1 = fmaf(wgt[1][q].y, hv.y, s1);
        s1 = fmaf(wgt[1][q].z, hv.z, s1); s1 = fmaf(wgt[1][q].w, hv.w, s1);
        s2 = fmaf(wgt[2][q].x, hv.x, s2); s2 = fmaf(wgt[2][q].y, hv.y, s2);
        s2 = fmaf(wgt[2][q].z, hv.z, s2); s2 = fmaf(wgt[2][q].w, hv.w, s2);
        s3 = fmaf(wgt[3][q].x, hv.x, s3); s3 = fmaf(wgt[3][q].y, hv.y, s3);
        s3 = fmaf(wgt[3][q].z, hv.z, s3); s3 = fmaf(wgt[3][q].w, hv.w, s3);
      }
#pragma unroll
      for (int off = 32; off >= 1; off >>= 1) {
        s0 += __shfl_xor(s0, off, 64); s1 += __shfl_xor(s1, off, 64);
        s2 += __shfl_xor(s2, off, 64); s3 += __shfl_xor(s3, off, 64);
      }
      // lanes 0..3 hold gate sums i,f,g,o -> parallel activations
      float act = 0.f;
      if (lane < 4) {
        float sel = (lane == 0) ? s0 : (lane == 1) ? s1 : (lane == 2) ? s2 : s3;
        sel += preval;
        act = (lane == 2) ? fast_tanh(sel) : fast_sigm(sel);
      }
      float af = __shfl(act, 1, 64);
      float ag = __shfl(act, 2, 64);
      float ao = __shfl(act, 3, 64);
      if (lane == 0) {
        c_state = af * c_state + act * ag;      // act@lane0 = sigm(i)
        float h = ao * fast_tanh(c_state);
        AGENT_ST64(&pk0[(long)t * HID + u], pack_h(h, t + 1));
      }
    }
  } else {
    // ----------------------------- layer 1 -------------------------------
    const int u = (b - 128) * UPB + wave;
    float4 wi[4][4], wh[4][4];
#pragma unroll
    for (int g = 0; g < 4; g++)
#pragma unroll
      for (int q = 0; q < 4; q++) {
        long o = ((long)((g << 10) + u) << 10) + (q << 8) + (lane << 2);
        wi[g][q] = *(const float4*)(Wih1 + o);
        wh[g][q] = *(const float4*)(Whh1 + o);
      }
    float preval = 0.f;               // constant bias for this gate/unit
    if (lane < 4) preval = b1sum[(lane << 10) + u];
    float c_state = 0.f;              // valid in lane 0
    u64 t_last = 0, per = 0;

    for (int r = 1; r <= T_STEPS; r++) {   // computes h1[r-1]
      const int par = r & 1;
      const u64* p0 = pk0 + (long)(r - 1) * HID + 2 * tid;
      const u64* p1 = pk1 + (long)((r >= 2) ? (r - 2) : 0) * HID + 2 * tid;
      pace_wait(t_last, per);
      u64 a0, a1, b0 = 0, b1 = 0;
      if (r >= 2) {
        for (;;) {
          a0 = AGENT_LD64(p0); a1 = AGENT_LD64(p0 + 1);
          b0 = AGENT_LD64(p1); b1 = AGENT_LD64(p1 + 1);
          if (pkt_tag(a0) == r && pkt_tag(a1) == r &&
              pkt_tag(b0) == r - 1 && pkt_tag(b1) == r - 1) break;
          __builtin_amdgcn_s_sleep(1);
        }
      } else {
        for (;;) {
          a0 = AGENT_LD64(p0); a1 = AGENT_LD64(p0 + 1);
          if (pkt_tag(a0) == r && pkt_tag(a1) == r) break;
          __builtin_amdgcn_s_sleep(1);
        }
      }
      pace_update(&t_last, &per);
      *(float2*)&ha[par][2 * tid] = make_float2(pkt_val(a0), pkt_val(a1));
      *(float2*)&hb[par][2 * tid] = (r >= 2)
          ? make_float2(pkt_val(b0), pkt_val(b1))
          : make_float2(0.f, 0.f);
      __syncthreads();

      float s0 = 0.f, s1 = 0.f, s2 = 0.f, s3 = 0.f;
#pragma unroll
      for (int q = 0; q < 4; q++) {
        float4 va = *(const float4*)&ha[par][(q << 8) + (lane << 2)];
        float4 vb = *(const float4*)&hb[par][(q << 8) + (lane << 2)];
        s0 = fmaf(wi[0][q].x, va.x, s0); s0 = fmaf(wi[0][q].y, va.y, s0);
        s0 = fmaf(wi[0][q].z, va.z, s0); s0 = fmaf(wi[0][q].w, va.w, s0);
        s0 = fmaf(wh[0][q].x, vb.x, s0); s0 = fmaf(wh[0][q].y, vb.y, s0);
        s0 = fmaf(wh[0][q].z, vb.z, s0); s0 = fmaf(wh[0][q].w, vb.w, s0);
        s1 = fmaf(wi[1][q].x, va.x, s1); s1 = fmaf(wi[1][q].y, va.y, s1);
        s1 = fmaf(wi[1][q].z, va.z, s1); s1 = fmaf(wi[1][q].w, va.w, s1);
        s1 = fmaf(wh[1][q].x, vb.x, s1); s1 = fmaf(wh[1][q].y, vb.y, s1);
        s1 = fmaf(wh[1][q].z, vb.z, s1); s1 = fmaf(wh[1][q].w, vb.w, s1);
        s2 = fmaf(wi[2][q].x, va.x, s2); s2 = fmaf(wi[2][q].y, va.y, s2);
        s2 = fmaf(wi[2][q].z, va.z, s2); s2 = fmaf(wi[2][q].w, va.w, s2);
        s2 = fmaf(wh[2][q].x, vb.x, s2); s2 = fmaf(wh[2][q].y, vb.y, s2);
        s2 = fmaf(wh[2][q].z, vb.z, s2); s2 = fmaf(wh[2][q].w, vb.w, s2);
        s3 = fmaf(wi[3][q].x, va.x, s3); s3 = fmaf(wi[3][q].y, va.y, s3);
        s3 = fmaf(wi[3][q].z, va.z, s3); s3 = fmaf(wi[3][q].w, va.w, s3);
        s3 = fmaf(wh[3][q].x, vb.x, s3); s3 = fmaf(wh[3][q].y, vb.y, s3);
        s3 = fmaf(wh[3][q].z, vb.z, s3); s3 = fmaf(wh[3][q].w, vb.w, s3);
      }
#pragma unroll
      for (int off = 32; off >= 1; off >>= 1) {
        s0 += __shfl_xor(s0, off, 64); s1 += __shfl_xor(s1, off, 64);
        s2 += __shfl_xor(s2, off, 64); s3 += __shfl_xor(s3, off, 64);
      }
      float act = 0.f;
      if (lane < 4) {
        float sel = (lane == 0) ? s0 : (lane == 1) ? s1 : (lane == 2) ? s2 : s3;
        sel += preval;
        act = (lane == 2) ? fast_tanh(sel) : fast_sigm(sel);
      }
      float af = __shfl(act, 1, 64);
      float ag = __shfl(act, 2, 64);
      float ao = __shfl(act, 3, 64);
      if (lane == 0) {
        c_state = af * c_state + act * ag;
        float h = ao * fast_tanh(c_state);
        AGENT_ST64(&pk1[(long)(r - 1) * HID + u], pack_h(h, r));
        h1_hist[(long)(r - 1) * HID + u] = h;   // off-path, for out GEMM
      }
    }
  }
}

extern "C" void kernel_launch(void* const* d_in, const int* in_sizes, int n_in,
                              void* d_out, int out_size, void* d_ws, size_t ws_size,
                              hipStream_t stream) {
  const float* inputs = (const float*)d_in[0];
  const float* W_in  = (const float*)d_in[1];
  const float* b_in  = (const float*)d_in[2];
  const float* W_ih0 = (const float*)d_in[3];
  const float* W_hh0 = (const float*)d_in[4];
  const float* b_ih0 = (const float*)d_in[5];
  const float* b_hh0 = (const float*)d_in[6];
  const float* W_ih1 = (const float*)d_in[7];
  const float* W_hh1 = (const float*)d_in[8];
  const float* b_ih1 = (const float*)d_in[9];
  const float* b_hh1 = (const float*)d_in[10];
  const float* W_out = (const float*)d_in[11];
  const float* b_out = (const float*)d_in[12];
  float* out = (float*)d_out;

  char* ws = (char*)d_ws;
  float* pre_big = (float*)(ws);                          // [0,64) MB: pre0
  u64*   pk0     = (u64*)  (ws + ((size_t)64 << 20));     // [64,96) MB
  u64*   pk1     = (u64*)  (ws + ((size_t)96 << 20));     // [96,128) MB
  float* zbuf    = (float*)(ws + ((size_t)128 << 20));    // [128,144) MB: z, then h1
  float* xg      = (float*)(ws + ((size_t)144 << 20));    // 1 MB
  float* bsum0   = (float*)(ws + ((size_t)145 << 20));    // 16 KB
  float* b1sum   = (float*)(ws + ((size_t)145 << 20) + 16384);

  // 0) invalidate packet tags (64 MB zeros) + gather x + combine biases
  k_clear<<<2048, 256, 0, stream>>>(pk0, (long)2 * T_STEPS * HID);
  k_prep<<<1024, 256, 0, stream>>>(inputs, b_ih0, b_hh0, b_ih1, b_hh1,
                                   xg, bsum0, b1sum);
  // 1) z = x @ W_in^T + b_in            (4096 x 1024, K=64)
  gemm_nt<<<dim3(32, 8), 256, 0, stream>>>(xg, W_in, b_in, zbuf,
                                           T_STEPS, HID, 64, 0);
  // 2) pre0 = z @ W_ih0^T + (b_ih0+b_hh0)   (4096 x 4096, K=1024)
  gemm_nt<<<dim3(32, 32), 256, 0, stream>>>(zbuf, W_ih0, bsum0, pre_big,
                                            T_STEPS, 4096, HID, 0);
  // 3) fused pipelined 2-layer recurrence (z already consumed; h1 -> zbuf)
  lstm_fused<<<NBLK, 512, 0, stream>>>(pre_big, W_hh0, W_ih1, W_hh1, b1sum,
                                       pk0, pk1, zbuf);
  // 4) y = h1 @ W_out^T + b_out, scattered to (samples, steps, out)
  gemm_nt<<<dim3(32, 1), 256, 0, stream>>>(zbuf, W_out, b_out, out,
                                           T_STEPS, 64, HID, 1);
}

// Round 3
// 16684.200 us; speedup vs baseline: 1.0869x; 1.0869x over previous
//
#include <hip/hip_runtime.h>
#include <math.h>

// ---------------------------------------------------------------------------
// SimpleRNN (2-layer LSTM, H=1024, T=4096 sequential steps, batch=1 effective)
//
//   k_clear    : zero the packet buffers (tags must start invalid)
//   k_prep     : gather x (step-major), combine biases
//   gemm_nt    : C[M,N] = A[M,K] @ B[N,K]^T + bias
//   lstm_fused : ONE persistent 256-block kernel. R9: BOTH layers in EVERY
//                block (4 units each). SYNC = DATA: h travels as 8-byte
//                packets {float h, int tag} via relaxed agent-scope stores.
//
//   R8 post-mortem (17.3ms): float4 LDS reads = 8-way bank conflict (1.7e7),
//   8B scattered stores = 4x write amplification + serialized detect,
//   halved occupancy. All three reverted here.
//   R9 design: the pk0 chain is the ONLY chain. Per round the on-chain
//   segment is just: detect -> B1 -> L0 dot (16 rows/block, 4-way k-split:
//   4 stride-64 ds_read_b32 + 16 FMA per lane) -> B2a -> parallel 16-lane
//   tail -> 32B-aligned coalesced packet store. L1 work (Wih1 reuses the
//   ha LDS copy; Whh1 operand is a full round stale) executes in the
//   store->detect shadow. R7 pacing retained. Stride-64 LDS (conflict-free,
//   R6-proven), 1024 thr/block, 1 block/CU.
// ---------------------------------------------------------------------------

#define T_STEPS 4096
#define HID 1024
#define UPB 4            // units per block PER LAYER (256 blocks x 4 = 1024)
#define NBLK 256         // persistent blocks (all do both layers)

typedef unsigned long long u64;

#define AGENT_LD64(p) __hip_atomic_load((p), __ATOMIC_RELAXED, __HIP_MEMORY_SCOPE_AGENT)
#define AGENT_ST64(p, v) __hip_atomic_store((p), (v), __ATOMIC_RELAXED, __HIP_MEMORY_SCOPE_AGENT)

__device__ __forceinline__ u64 pack_h(float h, int tag) {
  return (u64)__float_as_uint(h) | ((u64)(unsigned)tag << 32);
}
__device__ __forceinline__ float pkt_val(u64 v) { return __uint_as_float((unsigned)v); }
__device__ __forceinline__ int pkt_tag(u64 v) { return (int)(v >> 32); }

__device__ __forceinline__ float fast_sigm(float x) {
  return __builtin_amdgcn_rcpf(1.f + __expf(-x));
}
__device__ __forceinline__ float fast_tanh(float x) {
  return 2.f * __builtin_amdgcn_rcpf(1.f + __expf(-2.f * x)) - 1.f;
}

// Pace: sleep (no memory traffic) until ~half the expected period has
// elapsed since the previous detect. per==0 disables (warmup rounds).
__device__ __forceinline__ void pace_wait(u64 t_last, u64 per) {
  if (per) {
    u64 target = t_last + (per >> 1);
    while ((long long)(__builtin_amdgcn_s_memrealtime() - target) < 0)
      __builtin_amdgcn_s_sleep(2);
  }
}
// EWMA period update (clamped against scheduler hiccups).
__device__ __forceinline__ void pace_update(u64* t_last, u64* per) {
  u64 now = __builtin_amdgcn_s_memrealtime();
  if (*t_last) {
    u64 d = now - *t_last;
    if (d > 1024) d = 1024;                 // ~10 us cap @100 MHz wall clock
    *per = *per ? ((*per * 3 + d) >> 2) : d;
  }
  *t_last = now;
}

__global__ void k_clear(u64* __restrict__ p, long n) {
  long i = (long)blockIdx.x * blockDim.x + threadIdx.x;
  long stride = (long)gridDim.x * blockDim.x;
  for (; i < n; i += stride) p[i] = 0ULL;
}

__global__ void k_prep(const float* __restrict__ inputs,
                       const float* __restrict__ b_ih0, const float* __restrict__ b_hh0,
                       const float* __restrict__ b_ih1, const float* __restrict__ b_hh1,
                       float* __restrict__ xg, float* __restrict__ bsum0,
                       float* __restrict__ b1sum) {
  int i = blockIdx.x * 256 + threadIdx.x;   // grid covers 262144
  if (i < T_STEPS * 64) {
    int t = i >> 6, d = i & 63;
    // x[t] = inputs[sample = t%32, step = t/32, :]
    xg[i] = inputs[(t & 31) * 8192 + (t >> 5) * 64 + d];
  }
  if (i < 4096) {
    bsum0[i] = b_ih0[i] + b_hh0[i];
    b1sum[i] = b_ih1[i] + b_hh1[i];
  }
}

// C = A @ B^T + bias.  A: M x K, B: N x K (both row-major, K contiguous).
// 128x128 tile, BK=8, 256 threads, 8x8 micro-tile per thread.
__global__ __launch_bounds__(256) void gemm_nt(
    const float* __restrict__ A, const float* __restrict__ B,
    const float* __restrict__ bias, float* __restrict__ C,
    int M, int N, int K, int mode) {
  __shared__ float As[8][128];
  __shared__ float Bs[8][128];
  const int tid = threadIdx.x;
  const int bm = blockIdx.x * 128;
  const int bn = blockIdx.y * 128;
  const int tm = tid >> 4;
  const int tn = tid & 15;
  const int lr = tid >> 1;
  const int lk = (tid & 1) * 4;

  float acc[8][8];
#pragma unroll
  for (int i = 0; i < 8; i++)
#pragma unroll
    for (int j = 0; j < 8; j++) acc[i][j] = 0.f;

  const float* Ap = A + (long)(bm + lr) * K + lk;
  const bool bvalid = (bn + lr) < N;
  const float* Bp = B + (long)(bvalid ? (bn + lr) : 0) * K + lk;

  for (int k0 = 0; k0 < K; k0 += 8) {
    float4 av = *(const float4*)(Ap + k0);
    float4 bv = bvalid ? *(const float4*)(Bp + k0) : make_float4(0.f, 0.f, 0.f, 0.f);
    As[lk + 0][lr] = av.x; As[lk + 1][lr] = av.y;
    As[lk + 2][lr] = av.z; As[lk + 3][lr] = av.w;
    Bs[lk + 0][lr] = bv.x; Bs[lk + 1][lr] = bv.y;
    Bs[lk + 2][lr] = bv.z; Bs[lk + 3][lr] = bv.w;
    __syncthreads();
#pragma unroll
    for (int kk = 0; kk < 8; kk++) {
      float a[8], b[8];
      *(float4*)&a[0] = *(const float4*)&As[kk][tm * 8];
      *(float4*)&a[4] = *(const float4*)&As[kk][tm * 8 + 4];
      *(float4*)&b[0] = *(const float4*)&Bs[kk][tn * 8];
      *(float4*)&b[4] = *(const float4*)&Bs[kk][tn * 8 + 4];
#pragma unroll
      for (int i = 0; i < 8; i++)
#pragma unroll
        for (int j = 0; j < 8; j++) acc[i][j] = fmaf(a[i], b[j], acc[i][j]);
    }
    __syncthreads();
  }

  const int n0 = bn + tn * 8;
  if (n0 < N) {
    float bb[8];
#pragma unroll
    for (int j = 0; j < 8; j++) bb[j] = bias[n0 + j];
#pragma unroll
    for (int i = 0; i < 8; i++) {
      int m = bm + tm * 8 + i;
      float4 v0, v1;
      v0.x = acc[i][0] + bb[0]; v0.y = acc[i][1] + bb[1];
      v0.z = acc[i][2] + bb[2]; v0.w = acc[i][3] + bb[3];
      v1.x = acc[i][4] + bb[4]; v1.y = acc[i][5] + bb[5];
      v1.z = acc[i][6] + bb[6]; v1.w = acc[i][7] + bb[7];
      if (mode == 0) {
        long o = (long)m * N + n0;
        *(float4*)&C[o] = v0; *(float4*)&C[o + 4] = v1;
      } else {
        long o = (long)(m & 31) * 8192 + (long)(m >> 5) * 64 + n0;
        *(float4*)&C[o] = v0; *(float4*)&C[o + 4] = v1;
      }
    }
  }
}

// Fused 2-layer recurrence, merged: 256 blocks x 1024 threads (16 waves),
// each block owns units [4b, 4b+4) of BOTH layers.
// Wave w: unit lu = w&3, k-quarter kq = w>>2, ALL 4 gates of that unit over
// k in [256*kq, 256*kq+256). Lane covers k = 256*kq + lane + 64*m (stride-64
// ds_read_b32: conflict-free). Round t: detect h0[t-1] -> L0 dot -> parallel
// tail -> store pk0[t] (the chain); then L1 step t-1 (reuses ha in LDS +
// round-stale hb) in the store->detect shadow.
__global__ __launch_bounds__(1024) void lstm_fused(
    const float* __restrict__ pre0,   // T x 4096 (layer-0 biases included)
    const float* __restrict__ Whh0,   // 4096 x 1024
    const float* __restrict__ Wih1,   // 4096 x 1024
    const float* __restrict__ Whh1,   // 4096 x 1024
    const float* __restrict__ b1sum,  // 4096
    u64* __restrict__ pk0,            // T x 1024 packets {h0, tag=t+1}
    u64* __restrict__ pk1,            // T x 1024 packets {h1, tag=t+1}
    float* __restrict__ h1_hist) {    // T x 1024 plain (for output GEMM)
  __shared__ float ha[2][HID];        // 8 KB: h0[t-1], double-buffered
  __shared__ float hb[2][HID];        // 8 KB: h1[t-2], double-buffered
  __shared__ float scr0[4][16];       // L0 k-quarter partials [kq][g*4+lu]
  __shared__ float scr1[4][16];       // L1 k-quarter partials
  const int b = blockIdx.x;
  const int tid = threadIdx.x;
  const int wave = tid >> 6;
  const int lane = tid & 63;
  const int lu = wave & 3;            // this wave's unit (local)
  const int kq = wave >> 2;           // this wave's k-quarter
  const int u0 = b * UPB;             // first unit of block
  const int tg = lane >> 2;           // tail lane -> gate   (lane < 16)
  const int tlu = lane & 3;           // tail lane -> unit   (lane < 16)

  // Weights in VGPRs: row(g) = g*1024 + u0 + lu; element kq*256 + lane + 64m.
  float w0[4][4], wi[4][4], wh[4][4];
#pragma unroll
  for (int g = 0; g < 4; g++) {
    const long off = (((long)(g << 10) + u0 + lu) << 10) + (kq << 8) + lane;
#pragma unroll
    for (int m = 0; m < 4; m++) {
      w0[g][m] = Whh0[off + (m << 6)];
      wi[g][m] = Wih1[off + (m << 6)];
      wh[g][m] = Whh1[off + (m << 6)];
    }
  }
  float b1v = 0.f;
  if (wave == 1 && lane < 16) b1v = b1sum[(tg << 10) + u0 + tlu];
  float c0 = 0.f;                     // L0 cell state (wave0 lanes 0..3)
  float c1 = 0.f;                     // L1 cell state (wave1 lanes 0..3)
  u64 t_last = 0, per = 0;            // pacing state (100 MHz wall ticks)

  for (int t = 0; t <= T_STEPS; t++) {
    const int par = t & 1;
    float preval = 0.f;               // issue early: overlaps sleep/poll
    if (wave == 0 && lane < 16 && t < T_STEPS)
      preval = pre0[(long)t * 4096 + (tg << 10) + u0 + tlu];

    // ---- phase 1: detect h0[t-1] (chain) + h1[t-2] (stale, no-op wait) ----
    if (t > 0) {
      const u64* p0 = pk0 + (((long)(t - 1)) << 10) + tid;
      const u64* p1 = pk1 + (((long)((t >= 2) ? (t - 2) : 0)) << 10) + tid;
      pace_wait(t_last, per);
      u64 v0 = 0, v1 = 0;
      bool ok0 = false, ok1 = (t < 2);
      for (;;) {
        if (!ok0) { v0 = AGENT_LD64(p0); ok0 = (pkt_tag(v0) == t); }
        if (!ok1) { v1 = AGENT_LD64(p1); ok1 = (pkt_tag(v1) == t - 1); }
        if (ok0 && ok1) break;
        __builtin_amdgcn_s_sleep(1);
      }
      pace_update(&t_last, &per);
      ha[par][tid] = pkt_val(v0);
      hb[par][tid] = (t >= 2) ? pkt_val(v1) : 0.f;
    } else {
      ha[0][tid] = 0.f;
      hb[0][tid] = 0.f;
    }
    __syncthreads();                  // B1

    // ---- phase 2: L0 dot (on the chain; tiny: 4 LDS reads + 16 FMA) ------
    if (t < T_STEPS) {
      float s0 = 0.f, s1 = 0.f, s2 = 0.f, s3 = 0.f;
      const float* hap = &ha[par][(kq << 8) + lane];
#pragma unroll
      for (int m = 0; m < 4; m++) {
        float hv = hap[m << 6];
        s0 = fmaf(w0[0][m], hv, s0); s1 = fmaf(w0[1][m], hv, s1);
        s2 = fmaf(w0[2][m], hv, s2); s3 = fmaf(w0[3][m], hv, s3);
      }
#pragma unroll
      for (int off = 32; off >= 1; off >>= 1) {
        s0 += __shfl_xor(s0, off, 64); s1 += __shfl_xor(s1, off, 64);
        s2 += __shfl_xor(s2, off, 64); s3 += __shfl_xor(s3, off, 64);
      }
      if (lane < 4) {
        float v = (lane == 0) ? s0 : (lane == 1) ? s1 : (lane == 2) ? s2 : s3;
        scr0[kq][(lane << 2) + lu] = v;   // [kq][gate*4 + unit]
      }
    }
    __syncthreads();                  // B2a

    // ---- phase 3a: L0 tail + packet store (CHAIN OUTPUT, wave 0) ---------
    if (wave == 0 && lane < 16 && t < T_STEPS) {
      float sum = scr0[0][lane] + scr0[1][lane] + scr0[2][lane] +
                  scr0[3][lane] + preval;
      float a = (tg == 2) ? fast_tanh(sum) : fast_sigm(sum);  // parallel acts
      float af = __shfl(a, 4 + tlu, 64);
      float ag = __shfl(a, 8 + tlu, 64);
      float ao = __shfl(a, 12 + tlu, 64);
      if (lane < 4) {
        c0 = af * c0 + a * ag;                 // a@lane<4 = sigm(i)
        float h = ao * fast_tanh(c0);
        // 4 consecutive u64 from 4 lanes, 32B-aligned: one 32B transaction
        AGENT_ST64(&pk0[((long)t << 10) + u0 + lane], pack_h(h, t + 1));
      }
    }
    // ---- phase 3b: L1 dot (in the store->detect shadow, all waves) -------
    if (t >= 1) {
      float s0 = 0.f, s1 = 0.f, s2 = 0.f, s3 = 0.f;
      const float* hap = &ha[par][(kq << 8) + lane];
      const float* hbp = &hb[par][(kq << 8) + lane];
#pragma unroll
      for (int m = 0; m < 4; m++) {
        float av = hap[m << 6];
        float bv = hbp[m << 6];
        s0 = fmaf(wi[0][m], av, s0); s0 = fmaf(wh[0][m], bv, s0);
        s1 = fmaf(wi[1][m], av, s1); s1 = fmaf(wh[1][m], bv, s1);
        s2 = fmaf(wi[2][m], av, s2); s2 = fmaf(wh[2][m], bv, s2);
        s3 = fmaf(wi[3][m], av, s3); s3 = fmaf(wh[3][m], bv, s3);
      }
#pragma unroll
      for (int off = 32; off >= 1; off >>= 1) {
        s0 += __shfl_xor(s0, off, 64); s1 += __shfl_xor(s1, off, 64);
        s2 += __shfl_xor(s2, off, 64); s3 += __shfl_xor(s3, off, 64);
      }
      if (lane < 4) {
        float v = (lane == 0) ? s0 : (lane == 1) ? s1 : (lane == 2) ? s2 : s3;
        scr1[kq][(lane << 2) + lu] = v;
      }
    }
    __syncthreads();                  // B2b

    // ---- phase 4: L1 tail (off-chain, wave 1; others proceed to poll) ----
    if (wave == 1 && lane < 16 && t >= 1) {
      float sum = scr1[0][lane] + scr1[1][lane] + scr1[2][lane] +
                  scr1[3][lane] + b1v;
      float a = (tg == 2) ? fast_tanh(sum) : fast_sigm(sum);
      float af = __shfl(a, 4 + tlu, 64);
      float ag = __shfl(a, 8 + tlu, 64);
      float ao = __shfl(a, 12 + tlu, 64);
      if (lane < 4) {
        c1 = af * c1 + a * ag;
        float h = ao * fast_tanh(c1);
        AGENT_ST64(&pk1[((long)(t - 1) << 10) + u0 + lane], pack_h(h, t));
        h1_hist[((long)(t - 1) << 10) + u0 + lane] = h;  // for out GEMM
      }
    }
  }
}

extern "C" void kernel_launch(void* const* d_in, const int* in_sizes, int n_in,
                              void* d_out, int out_size, void* d_ws, size_t ws_size,
                              hipStream_t stream) {
  const float* inputs = (const float*)d_in[0];
  const float* W_in  = (const float*)d_in[1];
  const float* b_in  = (const float*)d_in[2];
  const float* W_ih0 = (const float*)d_in[3];
  const float* W_hh0 = (const float*)d_in[4];
  const float* b_ih0 = (const float*)d_in[5];
  const float* b_hh0 = (const float*)d_in[6];
  const float* W_ih1 = (const float*)d_in[7];
  const float* W_hh1 = (const float*)d_in[8];
  const float* b_ih1 = (const float*)d_in[9];
  const float* b_hh1 = (const float*)d_in[10];
  const float* W_out = (const float*)d_in[11];
  const float* b_out = (const float*)d_in[12];
  float* out = (float*)d_out;

  char* ws = (char*)d_ws;
  float* pre_big = (float*)(ws);                          // [0,64) MB: pre0
  u64*   pk0     = (u64*)  (ws + ((size_t)64 << 20));     // [64,96) MB
  u64*   pk1     = (u64*)  (ws + ((size_t)96 << 20));     // [96,128) MB
  float* zbuf    = (float*)(ws + ((size_t)128 << 20));    // [128,144) MB: z, then h1
  float* xg      = (float*)(ws + ((size_t)144 << 20));    // 1 MB
  float* bsum0   = (float*)(ws + ((size_t)145 << 20));    // 16 KB
  float* b1sum   = (float*)(ws + ((size_t)145 << 20) + 16384);

  // 0) invalidate packet tags (64 MB zeros) + gather x + combine biases
  k_clear<<<2048, 256, 0, stream>>>(pk0, (long)2 * T_STEPS * HID);
  k_prep<<<1024, 256, 0, stream>>>(inputs, b_ih0, b_hh0, b_ih1, b_hh1,
                                   xg, bsum0, b1sum);
  // 1) z = x @ W_in^T + b_in            (4096 x 1024, K=64)
  gemm_nt<<<dim3(32, 8), 256, 0, stream>>>(xg, W_in, b_in, zbuf,
                                           T_STEPS, HID, 64, 0);
  // 2) pre0 = z @ W_ih0^T + (b_ih0+b_hh0)   (4096 x 4096, K=1024)
  gemm_nt<<<dim3(32, 32), 256, 0, stream>>>(zbuf, W_ih0, bsum0, pre_big,
                                            T_STEPS, 4096, HID, 0);
  // 3) fused merged 2-layer recurrence (h1 -> zbuf)
  lstm_fused<<<NBLK, 1024, 0, stream>>>(pre_big, W_hh0, W_ih1, W_hh1, b1sum,
                                        pk0, pk1, zbuf);
  // 4) y = h1 @ W_out^T + b_out, scattered to (samples, steps, out)
  gemm_nt<<<dim3(32, 1), 256, 0, stream>>>(zbuf, W_out, b_out, out,
                                           T_STEPS, 64, HID, 1);
}

// Round 4
// 9971.669 us; speedup vs baseline: 1.8186x; 1.6732x over previous
//
#include <hip/hip_runtime.h>
#include <math.h>

// ---------------------------------------------------------------------------
// SimpleRNN (2-layer LSTM, H=1024, T=4096 sequential steps, batch=1 effective)
//
//   k_clear    : zero the packet buffers (tags must start invalid)
//   k_prep     : gather x (step-major), combine biases
//   gemm_nt    : C[M,N] = A[M,K] @ B[N,K]^T + bias
//   lstm_fused : persistent 256-block kernel, 128 L0 + 128 L1 blocks (R7
//                split skeleton, proven round 2.30us). SYNC = DATA: h moves
//                as 8-byte packets {float h, int tag}, relaxed agent-scope.
//
//   R9 post-mortem: merged-layer design put pk1 store->visibility ON the
//   chain (peers store it ~0ns before the poll) + 3rd barrier + 256-wide
//   all-to-all -> round 3.9us. Reverted.
//   R10 (this): R7 skeleton + two chain cuts, memory patterns untouched:
//     a) L1 dot split: Wih1@h0[r] computed OFF-chain in the store->detect
//        shadow (h0 is a full round stale; per-lane partials kept in regs,
//        no reduce). On-chain dot = Whh1 only (16 reads + 32 FMA, = L0).
//        L1 chain poll is now single-tag (pk1 only).
//     b) Parallel tails: 32 lanes compute the 4 gates' activations
//        concurrently (1 transcendental vs serial ~6), combined by 3
//        in-wave shuffles; pre0/bias live in registers (pre_lds deleted).
//   Stores stay 64B contiguous (tid<8), LDS reads stay stride-64 b32
//   (conflict-free), 1024 thr/block, R7 EWMA pacing on the chain polls.
// ---------------------------------------------------------------------------

#define T_STEPS 4096
#define HID 1024
#define UPB 8            // hidden units per block
#define NBLK 256         // persistent blocks (128 per layer)

typedef unsigned long long u64;

#define AGENT_LD64(p) __hip_atomic_load((p), __ATOMIC_RELAXED, __HIP_MEMORY_SCOPE_AGENT)
#define AGENT_ST64(p, v) __hip_atomic_store((p), (v), __ATOMIC_RELAXED, __HIP_MEMORY_SCOPE_AGENT)

__device__ __forceinline__ u64 pack_h(float h, int tag) {
  return (u64)__float_as_uint(h) | ((u64)(unsigned)tag << 32);
}
__device__ __forceinline__ float pkt_val(u64 v) { return __uint_as_float((unsigned)v); }
__device__ __forceinline__ int pkt_tag(u64 v) { return (int)(v >> 32); }

__device__ __forceinline__ float fast_sigm(float x) {
  return __builtin_amdgcn_rcpf(1.f + __expf(-x));
}
__device__ __forceinline__ float fast_tanh(float x) {
  return 2.f * __builtin_amdgcn_rcpf(1.f + __expf(-2.f * x)) - 1.f;
}

// Pace: sleep (no memory traffic) until ~half the expected period has
// elapsed since the previous detect. per==0 disables (warmup rounds).
__device__ __forceinline__ void pace_wait(u64 t_last, u64 per) {
  if (per) {
    u64 target = t_last + (per >> 1);
    while ((long long)(__builtin_amdgcn_s_memrealtime() - target) < 0)
      __builtin_amdgcn_s_sleep(2);
  }
}
// EWMA period update (clamped against scheduler hiccups).
__device__ __forceinline__ void pace_update(u64* t_last, u64* per) {
  u64 now = __builtin_amdgcn_s_memrealtime();
  if (*t_last) {
    u64 d = now - *t_last;
    if (d > 1024) d = 1024;                 // ~10 us cap @100 MHz wall clock
    *per = *per ? ((*per * 3 + d) >> 2) : d;
  }
  *t_last = now;
}

__global__ void k_clear(u64* __restrict__ p, long n) {
  long i = (long)blockIdx.x * blockDim.x + threadIdx.x;
  long stride = (long)gridDim.x * blockDim.x;
  for (; i < n; i += stride) p[i] = 0ULL;
}

__global__ void k_prep(const float* __restrict__ inputs,
                       const float* __restrict__ b_ih0, const float* __restrict__ b_hh0,
                       const float* __restrict__ b_ih1, const float* __restrict__ b_hh1,
                       float* __restrict__ xg, float* __restrict__ bsum0,
                       float* __restrict__ b1sum) {
  int i = blockIdx.x * 256 + threadIdx.x;   // grid covers 262144
  if (i < T_STEPS * 64) {
    int t = i >> 6, d = i & 63;
    // x[t] = inputs[sample = t%32, step = t/32, :]
    xg[i] = inputs[(t & 31) * 8192 + (t >> 5) * 64 + d];
  }
  if (i < 4096) {
    bsum0[i] = b_ih0[i] + b_hh0[i];
    b1sum[i] = b_ih1[i] + b_hh1[i];
  }
}

// C = A @ B^T + bias.  A: M x K, B: N x K (both row-major, K contiguous).
// 128x128 tile, BK=8, 256 threads, 8x8 micro-tile per thread.
__global__ __launch_bounds__(256) void gemm_nt(
    const float* __restrict__ A, const float* __restrict__ B,
    const float* __restrict__ bias, float* __restrict__ C,
    int M, int N, int K, int mode) {
  __shared__ float As[8][128];
  __shared__ float Bs[8][128];
  const int tid = threadIdx.x;
  const int bm = blockIdx.x * 128;
  const int bn = blockIdx.y * 128;
  const int tm = tid >> 4;
  const int tn = tid & 15;
  const int lr = tid >> 1;
  const int lk = (tid & 1) * 4;

  float acc[8][8];
#pragma unroll
  for (int i = 0; i < 8; i++)
#pragma unroll
    for (int j = 0; j < 8; j++) acc[i][j] = 0.f;

  const float* Ap = A + (long)(bm + lr) * K + lk;
  const bool bvalid = (bn + lr) < N;
  const float* Bp = B + (long)(bvalid ? (bn + lr) : 0) * K + lk;

  for (int k0 = 0; k0 < K; k0 += 8) {
    float4 av = *(const float4*)(Ap + k0);
    float4 bv = bvalid ? *(const float4*)(Bp + k0) : make_float4(0.f, 0.f, 0.f, 0.f);
    As[lk + 0][lr] = av.x; As[lk + 1][lr] = av.y;
    As[lk + 2][lr] = av.z; As[lk + 3][lr] = av.w;
    Bs[lk + 0][lr] = bv.x; Bs[lk + 1][lr] = bv.y;
    Bs[lk + 2][lr] = bv.z; Bs[lk + 3][lr] = bv.w;
    __syncthreads();
#pragma unroll
    for (int kk = 0; kk < 8; kk++) {
      float a[8], b[8];
      *(float4*)&a[0] = *(const float4*)&As[kk][tm * 8];
      *(float4*)&a[4] = *(const float4*)&As[kk][tm * 8 + 4];
      *(float4*)&b[0] = *(const float4*)&Bs[kk][tn * 8];
      *(float4*)&b[4] = *(const float4*)&Bs[kk][tn * 8 + 4];
#pragma unroll
      for (int i = 0; i < 8; i++)
#pragma unroll
        for (int j = 0; j < 8; j++) acc[i][j] = fmaf(a[i], b[j], acc[i][j]);
    }
    __syncthreads();
  }

  const int n0 = bn + tn * 8;
  if (n0 < N) {
    float bb[8];
#pragma unroll
    for (int j = 0; j < 8; j++) bb[j] = bias[n0 + j];
#pragma unroll
    for (int i = 0; i < 8; i++) {
      int m = bm + tm * 8 + i;
      float4 v0, v1;
      v0.x = acc[i][0] + bb[0]; v0.y = acc[i][1] + bb[1];
      v0.z = acc[i][2] + bb[2]; v0.w = acc[i][3] + bb[3];
      v1.x = acc[i][4] + bb[4]; v1.y = acc[i][5] + bb[5];
      v1.z = acc[i][6] + bb[6]; v1.w = acc[i][7] + bb[7];
      if (mode == 0) {
        long o = (long)m * N + n0;
        *(float4*)&C[o] = v0; *(float4*)&C[o + 4] = v1;
      } else {
        long o = (long)(m & 31) * 8192 + (long)(m >> 5) * 64 + n0;
        *(float4*)&C[o] = v0; *(float4*)&C[o + 4] = v1;
      }
    }
  }
}

// Fused 2-layer recurrence. 256 blocks x 1024 threads (16 waves), 1 block/CU.
// Wave w owns local rows 2w, 2w+1 (row rr: gate rr>>3, unit rr&7);
// lane covers k = lane + 64*m (stride-64 LDS reads: conflict-free).
__global__ __launch_bounds__(1024, 1) void lstm_fused(
    const float* __restrict__ pre0,   // T x 4096 (layer-0 biases included)
    const float* __restrict__ Whh0,   // 4096 x 1024
    const float* __restrict__ Wih1,   // 4096 x 1024
    const float* __restrict__ Whh1,   // 4096 x 1024
    const float* __restrict__ b1sum,  // 4096
    u64* __restrict__ pk0,            // T x 1024 packets {h0, tag=t+1}
    u64* __restrict__ pk1,            // T x 1024 packets {h1, tag=t+1}
    float* __restrict__ h1_hist) {    // T x 1024 plain (for output GEMM)
  __shared__ float ha_lds[HID];       // 4 KB
  __shared__ float hb_lds[HID];       // 4 KB (layer-1 only)
  __shared__ float scr[32];
  const int b = blockIdx.x;
  const int tid = threadIdx.x;
  const int wave = tid >> 6;          // wave w owns local rows 2w, 2w+1
  const int lane = tid & 63;

  if (b < 128) {
    // ----------------------------- layer 0 -------------------------------
    const int j0 = b * UPB;
    // weight rows in VGPRs: w0[m] = Whh0[row(2w)][lane+64m], w1 likewise
    float w0[16], w1[16];
    {
      int r0 = 2 * wave, r1 = 2 * wave + 1;
      const float* s0 = Whh0 + (long)((r0 >> 3) * HID + j0 + (r0 & 7)) * HID + lane;
      const float* s1 = Whh0 + (long)((r1 >> 3) * HID + j0 + (r1 & 7)) * HID + lane;
#pragma unroll
      for (int m = 0; m < 16; m++) { w0[m] = s0[m << 6]; w1[m] = s1[m << 6]; }
    }
    float c_state = 0.f;              // valid in tid 0..7
    u64 t_last = 0, per = 0;          // pacing state (100 MHz wall ticks)
    __syncthreads();

    for (int t = 0; t < T_STEPS; t++) {
      float preval = 0.f;             // in-register; load overlaps the poll
      if (tid < 32)
        preval = pre0[(long)t * 4096 + ((tid >> 3) << 10) + j0 + (tid & 7)];

      if (t > 0) {
        const u64* p = pk0 + (long)(t - 1) * HID + tid;
        pace_wait(t_last, per);
        u64 v;
        for (;;) {
          v = AGENT_LD64(p);
          if (pkt_tag(v) == t) break;
          __builtin_amdgcn_s_sleep(1);
        }
        pace_update(&t_last, &per);
        ha_lds[tid] = pkt_val(v);
      } else {
        ha_lds[tid] = 0.f;
      }
      __syncthreads();                // B1

      float s0 = 0.f, s1 = 0.f;
#pragma unroll
      for (int m = 0; m < 16; m++) {
        float hv = ha_lds[lane + (m << 6)];
        s0 = fmaf(w0[m], hv, s0);
        s1 = fmaf(w1[m], hv, s1);
      }
#pragma unroll
      for (int off = 32; off >= 1; off >>= 1) {
        s0 += __shfl_xor(s0, off, 64);
        s1 += __shfl_xor(s1, off, 64);
      }
      if (lane == 0) { scr[wave * 2] = s0; scr[wave * 2 + 1] = s1; }
      __syncthreads();                // B2

      // Parallel tail: 32 lanes of wave 0 = one (gate,unit) each.
      if (tid < 32) {
        float sum = scr[tid] + preval;
        float a = ((tid >> 3) == 2) ? fast_tanh(sum) : fast_sigm(sum);
        float af = __shfl(a,  8 + (tid & 7), 64);
        float ag = __shfl(a, 16 + (tid & 7), 64);
        float ao = __shfl(a, 24 + (tid & 7), 64);
        if (tid < 8) {                // a here = sigm(i) of unit tid
          c_state = af * c_state + a * ag;
          float h = ao * fast_tanh(c_state);
          // 8 consecutive u64 = one 64B line: coalesces into one write
          AGENT_ST64(&pk0[(long)t * HID + j0 + tid], pack_h(h, t + 1));
        }
      }
    }
  } else {
    // ----------------------------- layer 1 -------------------------------
    const int j0 = (b - 128) * UPB;
    float wi0[16], wi1[16], wh0[16], wh1[16];
    {
      int r0 = 2 * wave, r1 = 2 * wave + 1;
      long o0 = (long)((r0 >> 3) * HID + j0 + (r0 & 7)) * HID + lane;
      long o1 = (long)((r1 >> 3) * HID + j0 + (r1 & 7)) * HID + lane;
      const float* a0 = Wih1 + o0; const float* a1 = Wih1 + o1;
      const float* c0 = Whh1 + o0; const float* c1 = Whh1 + o1;
#pragma unroll
      for (int m = 0; m < 16; m++) {
        wi0[m] = a0[m << 6]; wi1[m] = a1[m << 6];
        wh0[m] = c0[m << 6]; wh1[m] = c1[m << 6];
      }
    }
    float b1v = 0.f;                  // in-register bias (gate,unit) of tid<32
    if (tid < 32) b1v = b1sum[((tid >> 3) << 10) + j0 + (tid & 7)];
    float c_state = 0.f;              // valid in tid 0..7
    u64 t_last = 0, per = 0;
    __syncthreads();

    // ---- setup: sA = Wih1 @ h0[0] per-lane partials (off-chain) ----------
    float sA0 = 0.f, sA1 = 0.f;
    {
      const u64* p = pk0 + tid;
      u64 v;
      for (;;) {
        v = AGENT_LD64(p);
        if (pkt_tag(v) == 1) break;
        __builtin_amdgcn_s_sleep(1);
      }
      ha_lds[tid] = pkt_val(v);
      __syncthreads();
#pragma unroll
      for (int m = 0; m < 16; m++) {
        float av = ha_lds[lane + (m << 6)];
        sA0 = fmaf(wi0[m], av, sA0);
        sA1 = fmaf(wi1[m], av, sA1);
      }
    }

    for (int r = 1; r <= T_STEPS; r++) {   // computes h1[r-1]
      // ---- chain: detect pk1[r-2] only (single tag) ----------------------
      if (r >= 2) {
        const u64* p = pk1 + (long)(r - 2) * HID + tid;
        pace_wait(t_last, per);
        u64 v;
        for (;;) {
          v = AGENT_LD64(p);
          if (pkt_tag(v) == r - 1) break;
          __builtin_amdgcn_s_sleep(1);
        }
        pace_update(&t_last, &per);
        hb_lds[tid] = pkt_val(v);
      } else {
        hb_lds[tid] = 0.f;
      }
      __syncthreads();                // B1

      // ---- on-chain dot: Whh1 term only (sA carried in registers) --------
      float s0 = sA0, s1 = sA1;
#pragma unroll
      for (int m = 0; m < 16; m++) {
        float bv = hb_lds[lane + (m << 6)];
        s0 = fmaf(wh0[m], bv, s0);
        s1 = fmaf(wh1[m], bv, s1);
      }
#pragma unroll
      for (int off = 32; off >= 1; off >>= 1) {
        s0 += __shfl_xor(s0, off, 64);
        s1 += __shfl_xor(s1, off, 64);
      }
      if (lane == 0) { scr[wave * 2] = s0; scr[wave * 2 + 1] = s1; }
      __syncthreads();                // B2

      // ---- parallel tail + chain store -----------------------------------
      if (tid < 32) {
        float sum = scr[tid] + b1v;
        float a = ((tid >> 3) == 2) ? fast_tanh(sum) : fast_sigm(sum);
        float af = __shfl(a,  8 + (tid & 7), 64);
        float ag = __shfl(a, 16 + (tid & 7), 64);
        float ao = __shfl(a, 24 + (tid & 7), 64);
        if (tid < 8) {
          c_state = af * c_state + a * ag;
          float h = ao * fast_tanh(c_state);
          AGENT_ST64(&pk1[(long)(r - 1) * HID + j0 + tid], pack_h(h, r));
          h1_hist[(long)(r - 1) * HID + j0 + tid] = h;   // for out GEMM
        }
      }

      // ---- off-chain (store->detect shadow): sA for next round -----------
      if (r < T_STEPS) {
        const u64* p = pk0 + (long)r * HID + tid;   // h0[r], one round stale
        u64 v;
        for (;;) {
          v = AGENT_LD64(p);
          if (pkt_tag(v) == r + 1) break;
          __builtin_amdgcn_s_sleep(1);
        }
        ha_lds[tid] = pkt_val(v);
        __syncthreads();              // B3 (off-chain)
        float n0 = 0.f, n1 = 0.f;
#pragma unroll
        for (int m = 0; m < 16; m++) {
          float av = ha_lds[lane + (m << 6)];
          n0 = fmaf(wi0[m], av, n0);
          n1 = fmaf(wi1[m], av, n1);
        }
        sA0 = n0; sA1 = n1;
      }
    }
  }
}

extern "C" void kernel_launch(void* const* d_in, const int* in_sizes, int n_in,
                              void* d_out, int out_size, void* d_ws, size_t ws_size,
                              hipStream_t stream) {
  const float* inputs = (const float*)d_in[0];
  const float* W_in  = (const float*)d_in[1];
  const float* b_in  = (const float*)d_in[2];
  const float* W_ih0 = (const float*)d_in[3];
  const float* W_hh0 = (const float*)d_in[4];
  const float* b_ih0 = (const float*)d_in[5];
  const float* b_hh0 = (const float*)d_in[6];
  const float* W_ih1 = (const float*)d_in[7];
  const float* W_hh1 = (const float*)d_in[8];
  const float* b_ih1 = (const float*)d_in[9];
  const float* b_hh1 = (const float*)d_in[10];
  const float* W_out = (const float*)d_in[11];
  const float* b_out = (const float*)d_in[12];
  float* out = (float*)d_out;

  char* ws = (char*)d_ws;
  float* pre_big = (float*)(ws);                          // [0,64) MB: pre0
  u64*   pk0     = (u64*)  (ws + ((size_t)64 << 20));     // [64,96) MB
  u64*   pk1     = (u64*)  (ws + ((size_t)96 << 20));     // [96,128) MB
  float* zbuf    = (float*)(ws + ((size_t)128 << 20));    // [128,144) MB: z, then h1
  float* xg      = (float*)(ws + ((size_t)144 << 20));    // 1 MB
  float* bsum0   = (float*)(ws + ((size_t)145 << 20));    // 16 KB
  float* b1sum   = (float*)(ws + ((size_t)145 << 20) + 16384);

  // 0) invalidate packet tags (64 MB zeros) + gather x + combine biases
  k_clear<<<2048, 256, 0, stream>>>(pk0, (long)2 * T_STEPS * HID);
  k_prep<<<1024, 256, 0, stream>>>(inputs, b_ih0, b_hh0, b_ih1, b_hh1,
                                   xg, bsum0, b1sum);
  // 1) z = x @ W_in^T + b_in            (4096 x 1024, K=64)
  gemm_nt<<<dim3(32, 8), 256, 0, stream>>>(xg, W_in, b_in, zbuf,
                                           T_STEPS, HID, 64, 0);
  // 2) pre0 = z @ W_ih0^T + (b_ih0+b_hh0)   (4096 x 4096, K=1024)
  gemm_nt<<<dim3(32, 32), 256, 0, stream>>>(zbuf, W_ih0, bsum0, pre_big,
                                            T_STEPS, 4096, HID, 0);
  // 3) fused pipelined 2-layer recurrence (h1 -> zbuf)
  lstm_fused<<<NBLK, 1024, 0, stream>>>(pre_big, W_hh0, W_ih1, W_hh1, b1sum,
                                        pk0, pk1, zbuf);
  // 4) y = h1 @ W_out^T + b_out, scattered to (samples, steps, out)
  gemm_nt<<<dim3(32, 1), 256, 0, stream>>>(zbuf, W_out, b_out, out,
                                           T_STEPS, 64, HID, 1);
}

// Round 5
// 9818.281 us; speedup vs baseline: 1.8470x; 1.0156x over previous
//
#include <hip/hip_runtime.h>
#include <math.h>

// ---------------------------------------------------------------------------
// SimpleRNN (2-layer LSTM, H=1024, T=4096 sequential steps, batch=1 effective)
//
//   k_clear    : zero the packet buffers (tags must start invalid)
//   k_prep     : gather x (step-major), combine biases
//   gemm_nt    : C[M,N] = A[M,K] @ B[N,K]^T + bias
//   lstm_fused : persistent 256-block kernel, 128 L0 + 128 L1 blocks (R7/R10
//                split skeleton). SYNC = DATA: h moves as 8-byte packets
//                {float h, int tag}, relaxed agent-scope.
//
//   R10 recap (9.07ms, round 2.22us): L1 dot split off-chain, parallel
//   32-lane tails, single-tag chain polls. Compute cuts moved the round only
//   2.30->2.22us => neither poll traffic (R7) nor on-chain compute (R10)
//   sets the period.
//   R11 (this): CLOCK-DROOP test. 85% of wall time is all-waves s_sleep
//   polling (VALUBusy 15%) -> DPM governor drops core clock; every
//   VALU/LDS/barrier segment of the chain pays ~2-3x cycle cost. Replace
//   every s_sleep wait (chain polls, off-chain poll, pace_wait) with a
//   dependent v_fmac_f32 spin (volatile asm, ~8 FMA/iter ~= s_sleep(1)
//   pacing) so all 256 blocks keep the SIMDs issuing. Protocol, memory
//   patterns, and data layout are UNCHANGED from R10.
// ---------------------------------------------------------------------------

#define T_STEPS 4096
#define HID 1024
#define UPB 8            // hidden units per block
#define NBLK 256         // persistent blocks (128 per layer)

typedef unsigned long long u64;

#define AGENT_LD64(p) __hip_atomic_load((p), __ATOMIC_RELAXED, __HIP_MEMORY_SCOPE_AGENT)
#define AGENT_ST64(p, v) __hip_atomic_store((p), (v), __ATOMIC_RELAXED, __HIP_MEMORY_SCOPE_AGENT)

__device__ __forceinline__ u64 pack_h(float h, int tag) {
  return (u64)__float_as_uint(h) | ((u64)(unsigned)tag << 32);
}
__device__ __forceinline__ float pkt_val(u64 v) { return __uint_as_float((unsigned)v); }
__device__ __forceinline__ int pkt_tag(u64 v) { return (int)(v >> 32); }

__device__ __forceinline__ float fast_sigm(float x) {
  return __builtin_amdgcn_rcpf(1.f + __expf(-x));
}
__device__ __forceinline__ float fast_tanh(float x) {
  return 2.f * __builtin_amdgcn_rcpf(1.f + __expf(-2.f * x)) - 1.f;
}

// Busy-spin unit: 8 dependent v_fmac_f32 (volatile -> always issued).
// Keeps the SIMD issue slots active during waits so the DPM governor holds
// a high clock state; ~30-50cy per call = poll pacing similar to s_sleep(1).
__device__ __forceinline__ void spin_fma(float* j) {
  const float eps = 1.0e-12f;
#pragma unroll
  for (int z = 0; z < 8; z++)
    asm volatile("v_fmac_f32 %0, %1, %1" : "+v"(*j) : "v"(eps));
}

// Pace: spin (no memory traffic, VALU busy) until ~half the expected period
// has elapsed since the previous detect. per==0 disables (warmup rounds).
__device__ __forceinline__ void pace_wait(u64 t_last, u64 per, float* j) {
  if (per) {
    u64 target = t_last + (per >> 1);
    while ((long long)(__builtin_amdgcn_s_memrealtime() - target) < 0)
      spin_fma(j);
  }
}
// EWMA period update (clamped against scheduler hiccups).
__device__ __forceinline__ void pace_update(u64* t_last, u64* per) {
  u64 now = __builtin_amdgcn_s_memrealtime();
  if (*t_last) {
    u64 d = now - *t_last;
    if (d > 1024) d = 1024;                 // ~10 us cap @100 MHz wall clock
    *per = *per ? ((*per * 3 + d) >> 2) : d;
  }
  *t_last = now;
}

__global__ void k_clear(u64* __restrict__ p, long n) {
  long i = (long)blockIdx.x * blockDim.x + threadIdx.x;
  long stride = (long)gridDim.x * blockDim.x;
  for (; i < n; i += stride) p[i] = 0ULL;
}

__global__ void k_prep(const float* __restrict__ inputs,
                       const float* __restrict__ b_ih0, const float* __restrict__ b_hh0,
                       const float* __restrict__ b_ih1, const float* __restrict__ b_hh1,
                       float* __restrict__ xg, float* __restrict__ bsum0,
                       float* __restrict__ b1sum) {
  int i = blockIdx.x * 256 + threadIdx.x;   // grid covers 262144
  if (i < T_STEPS * 64) {
    int t = i >> 6, d = i & 63;
    // x[t] = inputs[sample = t%32, step = t/32, :]
    xg[i] = inputs[(t & 31) * 8192 + (t >> 5) * 64 + d];
  }
  if (i < 4096) {
    bsum0[i] = b_ih0[i] + b_hh0[i];
    b1sum[i] = b_ih1[i] + b_hh1[i];
  }
}

// C = A @ B^T + bias.  A: M x K, B: N x K (both row-major, K contiguous).
// 128x128 tile, BK=8, 256 threads, 8x8 micro-tile per thread.
__global__ __launch_bounds__(256) void gemm_nt(
    const float* __restrict__ A, const float* __restrict__ B,
    const float* __restrict__ bias, float* __restrict__ C,
    int M, int N, int K, int mode) {
  __shared__ float As[8][128];
  __shared__ float Bs[8][128];
  const int tid = threadIdx.x;
  const int bm = blockIdx.x * 128;
  const int bn = blockIdx.y * 128;
  const int tm = tid >> 4;
  const int tn = tid & 15;
  const int lr = tid >> 1;
  const int lk = (tid & 1) * 4;

  float acc[8][8];
#pragma unroll
  for (int i = 0; i < 8; i++)
#pragma unroll
    for (int j = 0; j < 8; j++) acc[i][j] = 0.f;

  const float* Ap = A + (long)(bm + lr) * K + lk;
  const bool bvalid = (bn + lr) < N;
  const float* Bp = B + (long)(bvalid ? (bn + lr) : 0) * K + lk;

  for (int k0 = 0; k0 < K; k0 += 8) {
    float4 av = *(const float4*)(Ap + k0);
    float4 bv = bvalid ? *(const float4*)(Bp + k0) : make_float4(0.f, 0.f, 0.f, 0.f);
    As[lk + 0][lr] = av.x; As[lk + 1][lr] = av.y;
    As[lk + 2][lr] = av.z; As[lk + 3][lr] = av.w;
    Bs[lk + 0][lr] = bv.x; Bs[lk + 1][lr] = bv.y;
    Bs[lk + 2][lr] = bv.z; Bs[lk + 3][lr] = bv.w;
    __syncthreads();
#pragma unroll
    for (int kk = 0; kk < 8; kk++) {
      float a[8], b[8];
      *(float4*)&a[0] = *(const float4*)&As[kk][tm * 8];
      *(float4*)&a[4] = *(const float4*)&As[kk][tm * 8 + 4];
      *(float4*)&b[0] = *(const float4*)&Bs[kk][tn * 8];
      *(float4*)&b[4] = *(const float4*)&Bs[kk][tn * 8 + 4];
#pragma unroll
      for (int i = 0; i < 8; i++)
#pragma unroll
        for (int j = 0; j < 8; j++) acc[i][j] = fmaf(a[i], b[j], acc[i][j]);
    }
    __syncthreads();
  }

  const int n0 = bn + tn * 8;
  if (n0 < N) {
    float bb[8];
#pragma unroll
    for (int j = 0; j < 8; j++) bb[j] = bias[n0 + j];
#pragma unroll
    for (int i = 0; i < 8; i++) {
      int m = bm + tm * 8 + i;
      float4 v0, v1;
      v0.x = acc[i][0] + bb[0]; v0.y = acc[i][1] + bb[1];
      v0.z = acc[i][2] + bb[2]; v0.w = acc[i][3] + bb[3];
      v1.x = acc[i][4] + bb[4]; v1.y = acc[i][5] + bb[5];
      v1.z = acc[i][6] + bb[6]; v1.w = acc[i][7] + bb[7];
      if (mode == 0) {
        long o = (long)m * N + n0;
        *(float4*)&C[o] = v0; *(float4*)&C[o + 4] = v1;
      } else {
        long o = (long)(m & 31) * 8192 + (long)(m >> 5) * 64 + n0;
        *(float4*)&C[o] = v0; *(float4*)&C[o + 4] = v1;
      }
    }
  }
}

// Fused 2-layer recurrence. 256 blocks x 1024 threads (16 waves), 1 block/CU.
// Wave w owns local rows 2w, 2w+1 (row rr: gate rr>>3, unit rr&7);
// lane covers k = lane + 64*m (stride-64 LDS reads: conflict-free).
__global__ __launch_bounds__(1024, 1) void lstm_fused(
    const float* __restrict__ pre0,   // T x 4096 (layer-0 biases included)
    const float* __restrict__ Whh0,   // 4096 x 1024
    const float* __restrict__ Wih1,   // 4096 x 1024
    const float* __restrict__ Whh1,   // 4096 x 1024
    const float* __restrict__ b1sum,  // 4096
    u64* __restrict__ pk0,            // T x 1024 packets {h0, tag=t+1}
    u64* __restrict__ pk1,            // T x 1024 packets {h1, tag=t+1}
    float* __restrict__ h1_hist) {    // T x 1024 plain (for output GEMM)
  __shared__ float ha_lds[HID];       // 4 KB
  __shared__ float hb_lds[HID];       // 4 KB (layer-1 only)
  __shared__ float scr[32];
  const int b = blockIdx.x;
  const int tid = threadIdx.x;
  const int wave = tid >> 6;          // wave w owns local rows 2w, 2w+1
  const int lane = tid & 63;
  float junk = 0.f;                   // spin accumulator (kept live below)

  if (b < 128) {
    // ----------------------------- layer 0 -------------------------------
    const int j0 = b * UPB;
    // weight rows in VGPRs: w0[m] = Whh0[row(2w)][lane+64m], w1 likewise
    float w0[16], w1[16];
    {
      int r0 = 2 * wave, r1 = 2 * wave + 1;
      const float* s0 = Whh0 + (long)((r0 >> 3) * HID + j0 + (r0 & 7)) * HID + lane;
      const float* s1 = Whh0 + (long)((r1 >> 3) * HID + j0 + (r1 & 7)) * HID + lane;
#pragma unroll
      for (int m = 0; m < 16; m++) { w0[m] = s0[m << 6]; w1[m] = s1[m << 6]; }
    }
    float c_state = 0.f;              // valid in tid 0..7
    u64 t_last = 0, per = 0;          // pacing state (100 MHz wall ticks)
    __syncthreads();

    for (int t = 0; t < T_STEPS; t++) {
      float preval = 0.f;             // in-register; load overlaps the poll
      if (tid < 32)
        preval = pre0[(long)t * 4096 + ((tid >> 3) << 10) + j0 + (tid & 7)];

      if (t > 0) {
        const u64* p = pk0 + (long)(t - 1) * HID + tid;
        pace_wait(t_last, per, &junk);
        u64 v;
        for (;;) {
          v = AGENT_LD64(p);
          if (pkt_tag(v) == t) break;
          spin_fma(&junk);            // VALU-busy wait (clock hold)
        }
        pace_update(&t_last, &per);
        ha_lds[tid] = pkt_val(v);
      } else {
        ha_lds[tid] = 0.f;
      }
      __syncthreads();                // B1

      float s0 = 0.f, s1 = 0.f;
#pragma unroll
      for (int m = 0; m < 16; m++) {
        float hv = ha_lds[lane + (m << 6)];
        s0 = fmaf(w0[m], hv, s0);
        s1 = fmaf(w1[m], hv, s1);
      }
#pragma unroll
      for (int off = 32; off >= 1; off >>= 1) {
        s0 += __shfl_xor(s0, off, 64);
        s1 += __shfl_xor(s1, off, 64);
      }
      if (lane == 0) { scr[wave * 2] = s0; scr[wave * 2 + 1] = s1; }
      __syncthreads();                // B2

      // Parallel tail: 32 lanes of wave 0 = one (gate,unit) each.
      if (tid < 32) {
        float sum = scr[tid] + preval;
        float a = ((tid >> 3) == 2) ? fast_tanh(sum) : fast_sigm(sum);
        float af = __shfl(a,  8 + (tid & 7), 64);
        float ag = __shfl(a, 16 + (tid & 7), 64);
        float ao = __shfl(a, 24 + (tid & 7), 64);
        if (tid < 8) {                // a here = sigm(i) of unit tid
          c_state = af * c_state + a * ag;
          float h = ao * fast_tanh(c_state);
          // 8 consecutive u64 = one 64B line: coalesces into one write
          AGENT_ST64(&pk0[(long)t * HID + j0 + tid], pack_h(h, t + 1));
        }
      }
    }
    if (junk == 123456.789f) ha_lds[0] = junk;   // unreachable: keeps junk live
  } else {
    // ----------------------------- layer 1 -------------------------------
    const int j0 = (b - 128) * UPB;
    float wi0[16], wi1[16], wh0[16], wh1[16];
    {
      int r0 = 2 * wave, r1 = 2 * wave + 1;
      long o0 = (long)((r0 >> 3) * HID + j0 + (r0 & 7)) * HID + lane;
      long o1 = (long)((r1 >> 3) * HID + j0 + (r1 & 7)) * HID + lane;
      const float* a0 = Wih1 + o0; const float* a1 = Wih1 + o1;
      const float* c0 = Whh1 + o0; const float* c1 = Whh1 + o1;
#pragma unroll
      for (int m = 0; m < 16; m++) {
        wi0[m] = a0[m << 6]; wi1[m] = a1[m << 6];
        wh0[m] = c0[m << 6]; wh1[m] = c1[m << 6];
      }
    }
    float b1v = 0.f;                  // in-register bias (gate,unit) of tid<32
    if (tid < 32) b1v = b1sum[((tid >> 3) << 10) + j0 + (tid & 7)];
    float c_state = 0.f;              // valid in tid 0..7
    u64 t_last = 0, per = 0;
    __syncthreads();

    // ---- setup: sA = Wih1 @ h0[0] per-lane partials (off-chain) ----------
    float sA0 = 0.f, sA1 = 0.f;
    {
      const u64* p = pk0 + tid;
      u64 v;
      for (;;) {
        v = AGENT_LD64(p);
        if (pkt_tag(v) == 1) break;
        spin_fma(&junk);
      }
      ha_lds[tid] = pkt_val(v);
      __syncthreads();
#pragma unroll
      for (int m = 0; m < 16; m++) {
        float av = ha_lds[lane + (m << 6)];
        sA0 = fmaf(wi0[m], av, sA0);
        sA1 = fmaf(wi1[m], av, sA1);
      }
    }

    for (int r = 1; r <= T_STEPS; r++) {   // computes h1[r-1]
      // ---- chain: detect pk1[r-2] only (single tag) ----------------------
      if (r >= 2) {
        const u64* p = pk1 + (long)(r - 2) * HID + tid;
        pace_wait(t_last, per, &junk);
        u64 v;
        for (;;) {
          v = AGENT_LD64(p);
          if (pkt_tag(v) == r - 1) break;
          spin_fma(&junk);
        }
        pace_update(&t_last, &per);
        hb_lds[tid] = pkt_val(v);
      } else {
        hb_lds[tid] = 0.f;
      }
      __syncthreads();                // B1

      // ---- on-chain dot: Whh1 term only (sA carried in registers) --------
      float s0 = sA0, s1 = sA1;
#pragma unroll
      for (int m = 0; m < 16; m++) {
        float bv = hb_lds[lane + (m << 6)];
        s0 = fmaf(wh0[m], bv, s0);
        s1 = fmaf(wh1[m], bv, s1);
      }
#pragma unroll
      for (int off = 32; off >= 1; off >>= 1) {
        s0 += __shfl_xor(s0, off, 64);
        s1 += __shfl_xor(s1, off, 64);
      }
      if (lane == 0) { scr[wave * 2] = s0; scr[wave * 2 + 1] = s1; }
      __syncthreads();                // B2

      // ---- parallel tail + chain store -----------------------------------
      if (tid < 32) {
        float sum = scr[tid] + b1v;
        float a = ((tid >> 3) == 2) ? fast_tanh(sum) : fast_sigm(sum);
        float af = __shfl(a,  8 + (tid & 7), 64);
        float ag = __shfl(a, 16 + (tid & 7), 64);
        float ao = __shfl(a, 24 + (tid & 7), 64);
        if (tid < 8) {
          c_state = af * c_state + a * ag;
          float h = ao * fast_tanh(c_state);
          AGENT_ST64(&pk1[(long)(r - 1) * HID + j0 + tid], pack_h(h, r));
          h1_hist[(long)(r - 1) * HID + j0 + tid] = h;   // for out GEMM
        }
      }

      // ---- off-chain (store->detect shadow): sA for next round -----------
      if (r < T_STEPS) {
        const u64* p = pk0 + (long)r * HID + tid;   // h0[r], one round stale
        u64 v;
        for (;;) {
          v = AGENT_LD64(p);
          if (pkt_tag(v) == r + 1) break;
          spin_fma(&junk);
        }
        ha_lds[tid] = pkt_val(v);
        __syncthreads();              // B3 (off-chain)
        float n0 = 0.f, n1 = 0.f;
#pragma unroll
        for (int m = 0; m < 16; m++) {
          float av = ha_lds[lane + (m << 6)];
          n0 = fmaf(wi0[m], av, n0);
          n1 = fmaf(wi1[m], av, n1);
        }
        sA0 = n0; sA1 = n1;
      }
    }
    if (junk == 123456.789f) hb_lds[0] = junk;   // unreachable: keeps junk live
  }
}

extern "C" void kernel_launch(void* const* d_in, const int* in_sizes, int n_in,
                              void* d_out, int out_size, void* d_ws, size_t ws_size,
                              hipStream_t stream) {
  const float* inputs = (const float*)d_in[0];
  const float* W_in  = (const float*)d_in[1];
  const float* b_in  = (const float*)d_in[2];
  const float* W_ih0 = (const float*)d_in[3];
  const float* W_hh0 = (const float*)d_in[4];
  const float* b_ih0 = (const float*)d_in[5];
  const float* b_hh0 = (const float*)d_in[6];
  const float* W_ih1 = (const float*)d_in[7];
  const float* W_hh1 = (const float*)d_in[8];
  const float* b_ih1 = (const float*)d_in[9];
  const float* b_hh1 = (const float*)d_in[10];
  const float* W_out = (const float*)d_in[11];
  const float* b_out = (const float*)d_in[12];
  float* out = (float*)d_out;

  char* ws = (char*)d_ws;
  float* pre_big = (float*)(ws);                          // [0,64) MB: pre0
  u64*   pk0     = (u64*)  (ws + ((size_t)64 << 20));     // [64,96) MB
  u64*   pk1     = (u64*)  (ws + ((size_t)96 << 20));     // [96,128) MB
  float* zbuf    = (float*)(ws + ((size_t)128 << 20));    // [128,144) MB: z, then h1
  float* xg      = (float*)(ws + ((size_t)144 << 20));    // 1 MB
  float* bsum0   = (float*)(ws + ((size_t)145 << 20));    // 16 KB
  float* b1sum   = (float*)(ws + ((size_t)145 << 20) + 16384);

  // 0) invalidate packet tags (64 MB zeros) + gather x + combine biases
  k_clear<<<2048, 256, 0, stream>>>(pk0, (long)2 * T_STEPS * HID);
  k_prep<<<1024, 256, 0, stream>>>(inputs, b_ih0, b_hh0, b_ih1, b_hh1,
                                   xg, bsum0, b1sum);
  // 1) z = x @ W_in^T + b_in            (4096 x 1024, K=64)
  gemm_nt<<<dim3(32, 8), 256, 0, stream>>>(xg, W_in, b_in, zbuf,
                                           T_STEPS, HID, 64, 0);
  // 2) pre0 = z @ W_ih0^T + (b_ih0+b_hh0)   (4096 x 4096, K=1024)
  gemm_nt<<<dim3(32, 32), 256, 0, stream>>>(zbuf, W_ih0, bsum0, pre_big,
                                            T_STEPS, 4096, HID, 0);
  // 3) fused pipelined 2-layer recurrence (h1 -> zbuf)
  lstm_fused<<<NBLK, 1024, 0, stream>>>(pre_big, W_hh0, W_ih1, W_hh1, b1sum,
                                        pk0, pk1, zbuf);
  // 4) y = h1 @ W_out^T + b_out, scattered to (samples, steps, out)
  gemm_nt<<<dim3(32, 1), 256, 0, stream>>>(zbuf, W_out, b_out, out,
                                           T_STEPS, 64, HID, 1);
}